// Round 1
// baseline (37.954 us; speedup 1.0000x reference)
//
#include <hip/hip_runtime.h>

#define D_MODEL 512
#define D_TOK   504
#define EPS     1e-5f
#define SQRT_D  22.627416997969522f   // sqrt(512)

__global__ __launch_bounds__(256) void musical_emb_kernel(
    const int*   __restrict__ x,
    const float* __restrict__ tok_tab,   // [2048][504]
    const float* __restrict__ typ_tab,   // [5][8]
    const float* __restrict__ gamma,     // [512]
    const float* __restrict__ beta,      // [512]
    float*       __restrict__ out,       // [n_tokens][512]
    int n_tokens)
{
    const int wave = (int)((blockIdx.x * blockDim.x + threadIdx.x) >> 6);
    const int lane = (int)(threadIdx.x & 63);
    if (wave >= n_tokens) return;

    const int xi = x[wave];
    // branchless type index: ranges [0,128),[128,256),[256,512),[512,1024),[1024,2048)
    const int t = (xi >= 128) + (xi >= 256) + (xi >= 512) + (xi >= 1024);

    float v[8];
    if (lane < 63) {
        const float* row = tok_tab + (size_t)xi * D_TOK + (size_t)lane * 8;
        const float4 a = *reinterpret_cast<const float4*>(row);
        const float4 b = *reinterpret_cast<const float4*>(row + 4);
        v[0] = a.x; v[1] = a.y; v[2] = a.z; v[3] = a.w;
        v[4] = b.x; v[5] = b.y; v[6] = b.z; v[7] = b.w;
    } else {
        const float4* trow = reinterpret_cast<const float4*>(typ_tab + (size_t)t * 8);
        const float4 a = trow[0];
        const float4 b = trow[1];
        v[0] = a.x; v[1] = a.y; v[2] = a.z; v[3] = a.w;
        v[4] = b.x; v[5] = b.y; v[6] = b.z; v[7] = b.w;
    }

    float s = 0.f, s2 = 0.f;
#pragma unroll
    for (int i = 0; i < 8; ++i) { s += v[i]; s2 += v[i] * v[i]; }

    // 64-lane butterfly reduction
#pragma unroll
    for (int off = 32; off > 0; off >>= 1) {
        s  += __shfl_xor(s,  off, 64);
        s2 += __shfl_xor(s2, off, 64);
    }

    const float inv_n = 1.0f / (float)D_MODEL;
    const float mean  = s * inv_n;
    const float var   = s2 * inv_n - mean * mean;
    const float rs    = rsqrtf(var + EPS) * SQRT_D;   // fold in sqrt(d_model)

    const float4 g0 = *reinterpret_cast<const float4*>(gamma + lane * 8);
    const float4 g1 = *reinterpret_cast<const float4*>(gamma + lane * 8 + 4);
    const float4 b0 = *reinterpret_cast<const float4*>(beta  + lane * 8);
    const float4 b1 = *reinterpret_cast<const float4*>(beta  + lane * 8 + 4);

    float4 o0, o1;
    o0.x = (v[0] - mean) * rs * g0.x + b0.x * SQRT_D;
    o0.y = (v[1] - mean) * rs * g0.y + b0.y * SQRT_D;
    o0.z = (v[2] - mean) * rs * g0.z + b0.z * SQRT_D;
    o0.w = (v[3] - mean) * rs * g0.w + b0.w * SQRT_D;
    o1.x = (v[4] - mean) * rs * g1.x + b1.x * SQRT_D;
    o1.y = (v[5] - mean) * rs * g1.y + b1.y * SQRT_D;
    o1.z = (v[6] - mean) * rs * g1.z + b1.z * SQRT_D;
    o1.w = (v[7] - mean) * rs * g1.w + b1.w * SQRT_D;

    float* orow = out + (size_t)wave * D_MODEL + (size_t)lane * 8;
    *reinterpret_cast<float4*>(orow)     = o0;
    *reinterpret_cast<float4*>(orow + 4) = o1;
}

extern "C" void kernel_launch(void* const* d_in, const int* in_sizes, int n_in,
                              void* d_out, int out_size, void* d_ws, size_t ws_size,
                              hipStream_t stream) {
    const int*   x       = (const int*)d_in[0];
    const float* tok_tab = (const float*)d_in[1];
    const float* typ_tab = (const float*)d_in[2];
    const float* gamma   = (const float*)d_in[3];
    const float* beta    = (const float*)d_in[4];
    float*       out     = (float*)d_out;

    const int n_tokens = in_sizes[0];            // 16*4096 = 65536
    const int threads  = 256;                    // 4 waves -> 4 tokens per block
    const int blocks   = (n_tokens * 64 + threads - 1) / threads;

    musical_emb_kernel<<<blocks, threads, 0, stream>>>(
        x, tok_tab, typ_tab, gamma, beta, out, n_tokens);
}